// Round 8
// baseline (962.018 us; speedup 1.0000x reference)
//
#include <hip/hip_runtime.h>
#include <hip/hip_fp16.h>
#include <math.h>

// CapsNet forward. Round 18: launch-count attack. Per-kernel time sums to only
// ~200us of the 712us wall -> ~300us is launch-boundary overhead across 23
// serialized launches (~13us each). Fusions via last-block completion pattern:
//  - s_kernel + squash_v (+ mask on final round) -> route_s_kernel (atomicAdd
//    s-partials into svacc, global counter, last block squashes/zeros/resets;
//    round 3 also writes v-out and the decoder mask input). Kills 5 launches
//    + 63MB sbuf round-trip.
//  - mlp_part + mlp_reduce fused per layer via per-tile counters (last z-block
//    reduces + bias + act). Kills 3 launches.
// pconv reverted to its best form (R14: 166us; stagger/setprio/asm variants
// were all null -> structurally parked). 23 launches -> 12.

typedef __attribute__((ext_vector_type(8))) _Float16 half8;
typedef __attribute__((ext_vector_type(8))) short short8;
typedef __attribute__((ext_vector_type(4))) float floatx4;

__device__ __forceinline__ unsigned short f16bits(float v) {
    _Float16 h = (_Float16)v;
    unsigned short b;
    __builtin_memcpy(&b, &h, 2);
    return b;
}
__device__ __forceinline__ float f16back(unsigned short b) {
    _Float16 h;
    __builtin_memcpy(&h, &b, 2);
    return (float)h;
}
__device__ __forceinline__ void load_lds16(const void* g, void* l) {
    __builtin_amdgcn_global_load_lds(
        (const __attribute__((address_space(1))) unsigned int*)g,
        (__attribute__((address_space(3))) unsigned int*)l, 16, 0, 0);
}

// ---------------- conv1: x(256,1,28,28) * w(256,81) -> xpack NHWC fp16 hi/lo ----------------
__global__ __launch_bounds__(256, 2) void conv1_kernel(
    const float* __restrict__ x, const float* __restrict__ w,
    const float* __restrict__ bias, unsigned short* __restrict__ xpack)
{
    __shared__ float xs[784];
    __shared__ float wl[64 * 81];
    int t = threadIdx.x;
    int n = blockIdx.x;
    int cot = blockIdx.y;

    for (int j = t; j < 784; j += 256) xs[j] = x[n * 784 + j];
    {
        int co_s = t >> 2, k0 = (t & 3) * 21;
        const float* wsrc = w + (size_t)(cot * 64 + co_s) * 81;
        #pragma unroll
        for (int k = 0; k < 21; ++k)
            if (k0 + k < 81) wl[co_s * 81 + k0 + k] = wsrc[k0 + k];
    }
    __syncthreads();

    int co_l = t & 63, slot = t >> 6;
    int co = cot * 64 + co_l;
    float bv = bias[co];
    for (int r5 = 0; r5 < 5; ++r5) {
        int py = slot * 5 + r5;
        float acc[20];
        #pragma unroll
        for (int i = 0; i < 20; i++) acc[i] = bv;
        #pragma unroll
        for (int ky = 0; ky < 9; ++ky) {
            float xr[28];
            const float4* rowp = (const float4*)&xs[(py + ky) * 28];
            #pragma unroll
            for (int q = 0; q < 7; q++) {
                float4 v4 = rowp[q];
                xr[4*q] = v4.x; xr[4*q+1] = v4.y; xr[4*q+2] = v4.z; xr[4*q+3] = v4.w;
            }
            #pragma unroll
            for (int kx = 0; kx < 9; ++kx) {
                float wv = wl[co_l * 81 + ky * 9 + kx];
                #pragma unroll
                for (int px = 0; px < 20; ++px) acc[px] += wv * xr[px + kx];
            }
        }
        #pragma unroll
        for (int px = 0; px < 20; ++px) {
            float v = acc[px];
            unsigned short h = f16bits(v);
            unsigned short l = f16bits(v - f16back(h));
            size_t pix = (size_t)n * 400 + py * 20 + px;
            xpack[pix * 512 + co] = h;
            xpack[pix * 512 + 256 + co] = l;
        }
    }
}

// ---------------- weight repack: w[co][ci][9][9] -> frag-linear single fp16 ----------------
__global__ __launch_bounds__(256) void wpack_kernel(
    const float* __restrict__ w, unsigned short* __restrict__ wp)
{
    int tid = blockIdx.x * 256 + threadIdx.x;
    if (tid >= 648 * 16 * 64) return;
    int lane = tid & 63, g = (tid >> 6) & 15, gs = tid >> 10;
    int cb = gs & 7, kk = gs >> 3;
    int ky = kk / 9, kx = kk - ky * 9;
    int n16 = lane & 15, q = lane >> 4;
    int co = g * 16 + n16;
    unsigned short hv[8];
    #pragma unroll
    for (int j = 0; j < 8; ++j) {
        int ci = cb * 32 + q * 8 + j;
        hv[j] = f16bits(w[((size_t)co * 256 + ci) * 81 + ky * 9 + kx]);
    }
    unsigned short* dst = wp + ((size_t)gs * 16 + g) * 512 + lane * 8;
    *(short8*)dst = *(short8*)hv;
}

// ---------------- pconv GEMM: M48 x N256 x kc-split 4, 2-term fp16 (R14 best) ----------------
__global__ __launch_bounds__(256, 3) void pconv_mfma_kernel(
    const unsigned short* __restrict__ xp, const unsigned short* __restrict__ wp,
    __half* __restrict__ P6)
{
    __shared__ unsigned char lds[49152];        // 36KB used + pad (residency cap 3)
    int t = threadIdx.x;
    int lane = t & 63;
    int w = __builtin_amdgcn_readfirstlane(t >> 6);
    int mtile = blockIdx.x, kc = blockIdx.y;    // 192 mtiles x 48 rows, 4 kc of 162 gs
    int m16 = lane & 15, q = lane >> 4;

    unsigned int asrc[2];
    #pragma unroll
    for (int j = 0; j < 2; ++j) {
        int r = w * 16 + j * 8 + (lane >> 3);   // waves 0..2 stage rows 0..47
        if (r > 47) r = 47;                     // wave 3: arithmetic only, never loads
        int m = mtile * 48 + r;
        int n = m / 36, pos = m - n * 36;
        int oy = pos / 6, ox = pos - oy * 6;
        int pixbase = n * 400 + oy * 40 + ox * 2;
        int pp = (lane & 7) ^ (lane >> 3);       // XOR swizzle
        int partoff = (pp < 4) ? pp * 16 : 512 + (pp - 4) * 16;
        asrc[j] = (unsigned int)(pixbase * 1024 + partoff);
    }
    const char* xb = (const char*)xp;
    const char* wb = (const char*)wp;

    floatx4 acc[3][4];
    #pragma unroll
    for (int a = 0; a < 3; ++a)
        #pragma unroll
        for (int b = 0; b < 4; ++b) acc[a][b] = (floatx4){0.f, 0.f, 0.f, 0.f};

    int slot_hi = (q ^ (m16 & 7)) * 16;
    int slot_lo = slot_hi ^ 64;

    auto stageP = [&](int p, int buf) {
        if (w < 3) {
            #pragma unroll
            for (int e = 0; e < 2; ++e) {
                int s = 2 * p + e; if (s > 161) s = 161;
                int gs = kc * 162 + s;
                int kk = gs >> 3, cb = gs & 7;
                int ky = kk / 9, kx = kk - ky * 9;
                unsigned int delta = (unsigned int)((ky * 20 + kx) * 1024 + cb * 64);
                #pragma unroll
                for (int j = 0; j < 2; ++j)
                    load_lds16(xb + asrc[j] + delta,
                               (void*)(lds + buf * 12288 + e * 6144 + w * 2048 + j * 1024));
            }
        }
    };
    auto loadB = [&](int s, half8* B) {
        if (s > 161) s = 161;
        int gs = kc * 162 + s;
        #pragma unroll
        for (int c = 0; c < 4; ++c)
            B[c] = *(const half8*)(wb + ((size_t)gs * 16 + (w * 4 + c)) * 1024 + lane * 16);
    };
    auto compute = [&](int buf, int e, half8* B) {
        #pragma unroll
        for (int ms = 0; ms < 3; ++ms) {
            const char* base = (const char*)lds + buf * 12288 + e * 6144 + (ms * 16 + m16) * 128;
            half8 Ah = *(const half8*)(base + slot_hi);
            half8 Al = *(const half8*)(base + slot_lo);
            #pragma unroll
            for (int c = 0; c < 4; ++c) {
                acc[ms][c] = __builtin_amdgcn_mfma_f32_16x16x32_f16(Ah, B[c], acc[ms][c], 0, 0, 0);
                acc[ms][c] = __builtin_amdgcn_mfma_f32_16x16x32_f16(Al, B[c], acc[ms][c], 0, 0, 0);
            }
        }
    };

    half8 Ba0[4], Ba1[4], Bb0[4], Bb1[4];

    stageP(0, 0);
    stageP(1, 1);
    loadB(0, Ba0); loadB(1, Ba1);
    asm volatile("s_waitcnt vmcnt(12)" ::: "memory");
    __builtin_amdgcn_s_barrier();

#define PSTEP(PI, BUF, NBUF, C0, C1, N0, N1)                    \
    stageP((PI) + 2, NBUF);                                     \
    loadB(2 * (PI) + 2, N0); loadB(2 * (PI) + 3, N1);           \
    compute(BUF, 0, C0); compute(BUF, 1, C1);                   \
    asm volatile("s_waitcnt vmcnt(12)" ::: "memory");           \
    __builtin_amdgcn_s_barrier();

    for (int p = 0; p < 78; p += 6) {
        PSTEP(p + 0, 0, 2, Ba0, Ba1, Bb0, Bb1)
        PSTEP(p + 1, 1, 0, Bb0, Bb1, Ba0, Ba1)
        PSTEP(p + 2, 2, 1, Ba0, Ba1, Bb0, Bb1)
        PSTEP(p + 3, 0, 2, Bb0, Bb1, Ba0, Ba1)
        PSTEP(p + 4, 1, 0, Ba0, Ba1, Bb0, Bb1)
        PSTEP(p + 5, 2, 1, Bb0, Bb1, Ba0, Ba1)
    }
    PSTEP(78, 0, 2, Ba0, Ba1, Bb0, Bb1)
    PSTEP(79, 1, 0, Bb0, Bb1, Ba0, Ba1)
    PSTEP(80, 2, 1, Ba0, Ba1, Bb0, Bb1)
#undef PSTEP

    __half* outp = P6 + ((size_t)kc * 9216 + (size_t)mtile * 48) * 256;
    #pragma unroll
    for (int ms = 0; ms < 3; ++ms)
        #pragma unroll
        for (int r = 0; r < 4; ++r) {
            int ml = ms * 16 + q * 4 + r;
            #pragma unroll
            for (int c = 0; c < 4; ++c) {
                int co = w * 64 + c * 16 + m16;
                outp[ml * 256 + co] = __float2half(acc[ms][c][r]);
            }
        }
}

// ---------------- reduce 4 fp16 kc-partials + bias + squash over 8-dim capsules ----------------
__global__ __launch_bounds__(256) void squash_u_kernel(
    const __half* __restrict__ P6, const float* __restrict__ pb, float* __restrict__ u)
{
    int cap = blockIdx.x * 256 + threadIdx.x;
    int n = cap / 1152;
    int capl = cap - n * 1152;
    float z[8]; float n2 = 0.f;
    #pragma unroll
    for (int b = 0; b < 8; ++b) {
        int q2 = capl * 8 + b;
        int co = q2 / 36;
        int pos = q2 - co * 36;
        int m = n * 36 + pos;
        float s = 0.f;
        #pragma unroll
        for (int kc = 0; kc < 4; ++kc)
            s += __half2float(P6[((size_t)kc * 9216 + m) * 256 + co]);
        s += pb[co];
        z[b] = s; n2 += s * s;
    }
    float sc = sqrtf(n2) / (1.0f + n2);
    float4* op = (float4*)(u + (size_t)cap * 8);
    op[0] = make_float4(z[0]*sc, z[1]*sc, z[2]*sc, z[3]*sc);
    op[1] = make_float4(z[4]*sc, z[5]*sc, z[6]*sc, z[7]*sc);
}

// ---------------- fused routing step: s partials + softmax + (last block) squash/mask ----------------
// grid (8,48). atomicAdd s-partials into svacc; globally-last block squashes
// all 2560 (n,j) groups into v (and vout on final round), zeroes svacc,
// resets the counter, and computes the decoder mask input on the final round.
__global__ __launch_bounds__(256, 2) void route_s_kernel(
    const float* __restrict__ b, const float* __restrict__ u,
    const float* __restrict__ W, float* __restrict__ svacc,
    float* __restrict__ v, unsigned int* __restrict__ cnt,
    float* __restrict__ vout, float* __restrict__ rin)
{
    __shared__ float cs[24][10];
    __shared__ int lastf;
    int t = threadIdx.x;
    int a = t & 15, nl = t >> 4;
    int nt = blockIdx.x;
    int bz = blockIdx.y;
    int i0 = bz * 24;
    int n0 = nt * 32 + nl * 2;

    if (t < 24) {
        int i = i0 + t;
        float e[10], m = -1e30f;
        #pragma unroll
        for (int j = 0; j < 10; j++) { e[j] = b[i * 10 + j]; m = fmaxf(m, e[j]); }
        float sum = 0.f;
        #pragma unroll
        for (int j = 0; j < 10; j++) { e[j] = expf(e[j] - m); sum += e[j]; }
        float inv = 1.f / sum;
        #pragma unroll
        for (int j = 0; j < 10; j++) cs[t][j] = e[j] * inv;
    }
    __syncthreads();

    float acc[2][10];
    #pragma unroll
    for (int r = 0; r < 2; ++r)
        #pragma unroll
        for (int j = 0; j < 10; ++j) acc[r][j] = 0.f;

    for (int i = i0; i < i0 + 24; ++i) {
        float4 u0[2], u1[2];
        #pragma unroll
        for (int r = 0; r < 2; ++r) {
            const float4* up = (const float4*)&u[(size_t)(n0 + r) * 9216 + (size_t)i * 8];
            u0[r] = up[0]; u1[r] = up[1];
        }
        #pragma unroll
        for (int j = 0; j < 10; ++j) {
            const float4* wpt = (const float4*)&W[(((size_t)i * 10 + j) * 16 + a) * 8];
            float4 w0 = wpt[0], w1 = wpt[1];
            float cij = cs[i - i0][j];
            #pragma unroll
            for (int r = 0; r < 2; ++r) {
                float d = w0.x*u0[r].x + w0.y*u0[r].y + w0.z*u0[r].z + w0.w*u0[r].w
                        + w1.x*u1[r].x + w1.y*u1[r].y + w1.z*u1[r].z + w1.w*u1[r].w;
                acc[r][j] += cij * d;
            }
        }
    }
    #pragma unroll
    for (int r = 0; r < 2; ++r)
        #pragma unroll
        for (int j = 0; j < 10; ++j)
            atomicAdd(&svacc[(((size_t)(n0 + r) * 10 + j) * 16) + a], acc[r][j]);

    __threadfence();
    if (t == 0) lastf = (atomicAdd(cnt, 1u) == 8u * 48u - 1u) ? 1 : 0;
    __syncthreads();
    if (!lastf) return;
    __threadfence();

    // last block: squash all 2560 (n,j) groups; zero svacc for next round
    for (int pr = t; pr < 2560; pr += 256) {
        float4* sp = (float4*)&svacc[(size_t)pr * 16];
        float4 x0 = sp[0], x1 = sp[1], x2 = sp[2], x3 = sp[3];
        float n2 = x0.x*x0.x + x0.y*x0.y + x0.z*x0.z + x0.w*x0.w
                 + x1.x*x1.x + x1.y*x1.y + x1.z*x1.z + x1.w*x1.w
                 + x2.x*x2.x + x2.y*x2.y + x2.z*x2.z + x2.w*x2.w
                 + x3.x*x3.x + x3.y*x3.y + x3.z*x3.z + x3.w*x3.w;
        float sc = sqrtf(n2) / (1.0f + n2);
        float4 y0 = make_float4(x0.x*sc, x0.y*sc, x0.z*sc, x0.w*sc);
        float4 y1 = make_float4(x1.x*sc, x1.y*sc, x1.z*sc, x1.w*sc);
        float4 y2 = make_float4(x2.x*sc, x2.y*sc, x2.z*sc, x2.w*sc);
        float4 y3 = make_float4(x3.x*sc, x3.y*sc, x3.z*sc, x3.w*sc);
        float4* vp = (float4*)&v[(size_t)pr * 16];
        vp[0] = y0; vp[1] = y1; vp[2] = y2; vp[3] = y3;
        if (vout) {
            float4* op = (float4*)&vout[(size_t)pr * 16];
            op[0] = y0; op[1] = y1; op[2] = y2; op[3] = y3;
        }
        float4 z4 = make_float4(0.f, 0.f, 0.f, 0.f);
        sp[0] = z4; sp[1] = z4; sp[2] = z4; sp[3] = z4;
    }
    if (t == 0) atomicExch(cnt, 0u);

    if (rin) {
        __syncthreads();                         // v writes visible block-wide
        const float* vp = &v[(size_t)t * 160];   // thread t = image n
        int best = 0; float bestn2 = -1.f;
        #pragma unroll
        for (int j = 0; j < 10; ++j) {
            const float4* q4 = (const float4*)&vp[j * 16];
            float4 a0 = q4[0], a1 = q4[1], a2 = q4[2], a3 = q4[3];
            float n2 = a0.x*a0.x + a0.y*a0.y + a0.z*a0.z + a0.w*a0.w
                     + a1.x*a1.x + a1.y*a1.y + a1.z*a1.z + a1.w*a1.w
                     + a2.x*a2.x + a2.y*a2.y + a2.z*a2.z + a2.w*a2.w
                     + a3.x*a3.x + a3.y*a3.y + a3.z*a3.z + a3.w*a3.w;
            if (n2 > bestn2) { bestn2 = n2; best = j; }   // strict > = first max
        }
        float* rp = &rin[(size_t)t * 160];
        #pragma unroll
        for (int j = 0; j < 10; ++j) {
            const float4* q4 = (const float4*)&vp[j * 16];
            float4* o4 = (float4*)&rp[j * 16];
            if (j == best) { o4[0] = q4[0]; o4[1] = q4[1]; o4[2] = q4[2]; o4[3] = q4[3]; }
            else {
                float4 z4 = make_float4(0.f, 0.f, 0.f, 0.f);
                o4[0] = z4; o4[1] = z4; o4[2] = z4; o4[3] = z4;
            }
        }
    }
}

// ---------------- b[i,j] update, i-tile of 4 per block ----------------
__global__ __launch_bounds__(192) void bupd_kernel(
    const float* __restrict__ u, const float* __restrict__ v,
    const float* __restrict__ W, float* __restrict__ b)
{
    int i0 = blockIdx.x * 4;
    int n0 = blockIdx.y * 128;
    int t = threadIdx.x;
    if (t >= 160) return;
    int j = t >> 4, a = t & 15;
    float g4[4][8];
    #pragma unroll
    for (int g = 0; g < 4; ++g)
        #pragma unroll
        for (int k = 0; k < 8; ++k) g4[g][k] = 0.f;

    for (int n = n0; n < n0 + 128; ++n) {
        float vv = v[n * 160 + t];
        const float4* ub = (const float4*)&u[(size_t)n * 9216 + (size_t)i0 * 8];
        #pragma unroll
        for (int g = 0; g < 4; ++g) {
            float4 q0 = ub[g * 2], q1 = ub[g * 2 + 1];
            g4[g][0] += q0.x * vv; g4[g][1] += q0.y * vv; g4[g][2] += q0.z * vv; g4[g][3] += q0.w * vv;
            g4[g][4] += q1.x * vv; g4[g][5] += q1.y * vv; g4[g][6] += q1.z * vv; g4[g][7] += q1.w * vv;
        }
    }
    #pragma unroll
    for (int g = 0; g < 4; ++g) {
        int i = i0 + g;
        const float4* wpt = (const float4*)&W[(((size_t)i * 10 + j) * 16 + a) * 8];
        float4 w0 = wpt[0], w1 = wpt[1];
        float p = w0.x*g4[g][0] + w0.y*g4[g][1] + w0.z*g4[g][2] + w0.w*g4[g][3]
                + w1.x*g4[g][4] + w1.y*g4[g][5] + w1.z*g4[g][6] + w1.w*g4[g][7];
        p += __shfl_xor(p, 1);
        p += __shfl_xor(p, 2);
        p += __shfl_xor(p, 4);
        p += __shfl_xor(p, 8);
        if (a == 0) atomicAdd(&b[i * 10 + j], p);
    }
}

// ---------------- MLP fused: partial GEMM + last-z-block reduce/bias/act ----------------
template<int K, int KCH, int O, int ACT>
__global__ __launch_bounds__(256, 2) void mlp_fused_kernel(
    const float* __restrict__ X, const float* __restrict__ Wm,
    const float* __restrict__ bias, float* __restrict__ partial,
    float* __restrict__ out, unsigned int* __restrict__ cnts)
{
    __shared__ float XS[KCH * 16];
    __shared__ int lastf;
    const int KS = K / KCH;
    int t = threadIdx.x;
    int og = t & 63, ns = t >> 6;
    int n0 = blockIdx.x * 16;
    int o = blockIdx.y * 256 + og * 4;
    int o_c = min(o, O - 4);
    int ks = blockIdx.z;
    int kc0 = ks * KCH;

    for (int idx = t; idx < KCH * 16; idx += 256) {
        int k_l = idx >> 4, n_l = idx & 15;
        XS[k_l * 16 + n_l] = X[(size_t)(n0 + n_l) * K + kc0 + k_l];
    }
    __syncthreads();

    float acc[4][4];
    #pragma unroll
    for (int r = 0; r < 4; ++r)
        #pragma unroll
        for (int q = 0; q < 4; ++q) acc[r][q] = 0.f;

    #pragma unroll 8
    for (int k = 0; k < KCH; ++k) {
        float4 wv = *(const float4*)&Wm[(size_t)(kc0 + k) * O + o_c];
        float4 xs4 = *(const float4*)&XS[k * 16 + ns * 4];
        acc[0][0] += xs4.x * wv.x; acc[0][1] += xs4.x * wv.y; acc[0][2] += xs4.x * wv.z; acc[0][3] += xs4.x * wv.w;
        acc[1][0] += xs4.y * wv.x; acc[1][1] += xs4.y * wv.y; acc[1][2] += xs4.y * wv.z; acc[1][3] += xs4.y * wv.w;
        acc[2][0] += xs4.z * wv.x; acc[2][1] += xs4.z * wv.y; acc[2][2] += xs4.z * wv.z; acc[2][3] += xs4.z * wv.w;
        acc[3][0] += xs4.w * wv.x; acc[3][1] += xs4.w * wv.y; acc[3][2] += xs4.w * wv.z; acc[3][3] += xs4.w * wv.w;
    }

    if (o < O) {
        float* pp = partial + ((size_t)ks * 256 + n0 + ns * 4) * O + o;
        #pragma unroll
        for (int r = 0; r < 4; ++r)
            *(float4*)(pp + (size_t)r * O) = make_float4(acc[r][0], acc[r][1], acc[r][2], acc[r][3]);
    }

    __threadfence();
    int ci = blockIdx.y * gridDim.x + blockIdx.x;
    if (t == 0) lastf = (atomicAdd(&cnts[ci], 1u) == (unsigned)(KS - 1)) ? 1 : 0;
    __syncthreads();
    if (!lastf) return;
    __threadfence();

    if (o < O) {
        float4 bv = *(const float4*)&bias[o];
        #pragma unroll
        for (int r = 0; r < 4; ++r) {
            int n = n0 + ns * 4 + r;
            float4 s = make_float4(0.f, 0.f, 0.f, 0.f);
            for (int z = 0; z < KS; ++z) {
                float4 p = *(const float4*)&partial[((size_t)z * 256 + n) * O + o];
                s.x += p.x; s.y += p.y; s.z += p.z; s.w += p.w;
            }
            float rr[4] = {s.x + bv.x, s.y + bv.y, s.z + bv.z, s.w + bv.w};
            #pragma unroll
            for (int q = 0; q < 4; ++q)
                rr[q] = (ACT == 0) ? fmaxf(rr[q], 0.f) : (1.f / (1.f + expf(-rr[q])));
            *(float4*)&out[(size_t)n * O + o] = make_float4(rr[0], rr[1], rr[2], rr[3]);
        }
    }
    if (t == 0) atomicExch(&cnts[ci], 0u);
}

extern "C" void kernel_launch(void* const* d_in, const int* in_sizes, int n_in,
                              void* d_out, int out_size, void* d_ws, size_t ws_size,
                              hipStream_t stream)
{
    const float* x       = (const float*)d_in[0];
    const float* conv1_w = (const float*)d_in[1];
    const float* conv1_b = (const float*)d_in[2];
    const float* pconv_w = (const float*)d_in[3];
    const float* pconv_b = (const float*)d_in[4];
    const float* W_caps  = (const float*)d_in[5];
    const float* dec_w1  = (const float*)d_in[6];
    const float* dec_b1  = (const float*)d_in[7];
    const float* dec_w2  = (const float*)d_in[8];
    const float* dec_b2  = (const float*)d_in[9];
    const float* dec_w3  = (const float*)d_in[10];
    const float* dec_b3  = (const float*)d_in[11];
    float* out = (float*)d_out;

    float* ws = (float*)d_ws;
    size_t off = 0;
    auto alloc = [&](size_t nf) { float* p = ws + off; off += (nf + 63) & ~(size_t)63; return p; };
    unsigned short* xpack = (unsigned short*)alloc(26214400);  // 256*400*512 ushort
    unsigned short* wpack = (unsigned short*)alloc(2654208);   // 648*16*512 ushort
    __half* P6  = (__half*)alloc(4718592);   // 4*9216*256 fp16 partials
    float* u_in = alloc(2359296);
    float* bbuf = alloc(11520);              // |-- zeroed region start
    float* svacc = alloc(40960);             // |   s accumulator
    unsigned int* cnts = (unsigned int*)alloc(256);  // | 0..63 mlp tiles, 64 route
    float* vbuf = alloc(40960);
    float* rin  = alloc(40960);
    float* mpart = alloc(8 * 256 * 1024);
    float* h1   = alloc(131072);
    float* h2   = alloc(262144);

    // zero bbuf + svacc + cnts in one shot (contiguous, 64-float aligned sizes)
    hipMemsetAsync(bbuf, 0, (11520 + 40960 + 256) * sizeof(float), stream);

    wpack_kernel<<<(648 * 16 * 64 + 255) / 256, 256, 0, stream>>>(pconv_w, wpack);
    conv1_kernel<<<dim3(256, 4), 256, 0, stream>>>(x, conv1_w, conv1_b, xpack);
    pconv_mfma_kernel<<<dim3(192, 4), 256, 0, stream>>>(xpack, wpack, P6);
    squash_u_kernel<<<1152, 256, 0, stream>>>(P6, pconv_b, u_in);

    for (int r = 0; r < 4; ++r) {
        route_s_kernel<<<dim3(8, 48), 256, 0, stream>>>(
            bbuf, u_in, W_caps, svacc, vbuf, &cnts[64],
            (r == 3) ? out : nullptr, (r == 3) ? rin : nullptr);
        if (r < 3) bupd_kernel<<<dim3(288, 2), 192, 0, stream>>>(u_in, vbuf, W_caps, bbuf);
    }

    mlp_fused_kernel<160, 80, 512, 0><<<dim3(16, 2, 2), 256, 0, stream>>>(rin, dec_w1, dec_b1, mpart, h1, cnts);
    mlp_fused_kernel<512, 128, 1024, 0><<<dim3(16, 4, 4), 256, 0, stream>>>(h1, dec_w2, dec_b2, mpart, h2, cnts);
    mlp_fused_kernel<1024, 128, 784, 1><<<dim3(16, 4, 8), 256, 0, stream>>>(h2, dec_w3, dec_b3, mpart, out + 40960, cnts);
}

// Round 9
// 734.069 us; speedup vs baseline: 1.3105x; 1.3105x over previous
//
#include <hip/hip_runtime.h>
#include <hip/hip_fp16.h>
#include <math.h>

// CapsNet forward. Round 19: R18's fusions REVERTED (last-block fencing
// regressed 712->962: serial tails + device-wide dependency chains cost more
// than the launches they saved -> non-pconv time is real kernel time, not
// boundaries). This round: double the parallelism of the latency-bound
// routing kernels via pure tiling changes:
//   s_kernel: i-split 24->12/block, grid (8,96) = 768 blocks (was 384 = 1.5/CU)
//   bupd:     n-split 128->64/block, grid (288,4) = 1152 blocks (was 576)
//   squash_v: sums 96 partials (constant)
// pconv/conv1/squash_u/mask/mlp = exact R14/R17 best-measured forms.

typedef __attribute__((ext_vector_type(8))) _Float16 half8;
typedef __attribute__((ext_vector_type(8))) short short8;
typedef __attribute__((ext_vector_type(4))) float floatx4;

__device__ __forceinline__ unsigned short f16bits(float v) {
    _Float16 h = (_Float16)v;
    unsigned short b;
    __builtin_memcpy(&b, &h, 2);
    return b;
}
__device__ __forceinline__ float f16back(unsigned short b) {
    _Float16 h;
    __builtin_memcpy(&h, &b, 2);
    return (float)h;
}
__device__ __forceinline__ void load_lds16(const void* g, void* l) {
    __builtin_amdgcn_global_load_lds(
        (const __attribute__((address_space(1))) unsigned int*)g,
        (__attribute__((address_space(3))) unsigned int*)l, 16, 0, 0);
}

// ---------------- conv1: x(256,1,28,28) * w(256,81) -> xpack NHWC fp16 hi/lo ----------------
__global__ __launch_bounds__(256, 2) void conv1_kernel(
    const float* __restrict__ x, const float* __restrict__ w,
    const float* __restrict__ bias, unsigned short* __restrict__ xpack)
{
    __shared__ float xs[784];
    __shared__ float wl[64 * 81];
    int t = threadIdx.x;
    int n = blockIdx.x;
    int cot = blockIdx.y;

    for (int j = t; j < 784; j += 256) xs[j] = x[n * 784 + j];
    {
        int co_s = t >> 2, k0 = (t & 3) * 21;
        const float* wsrc = w + (size_t)(cot * 64 + co_s) * 81;
        #pragma unroll
        for (int k = 0; k < 21; ++k)
            if (k0 + k < 81) wl[co_s * 81 + k0 + k] = wsrc[k0 + k];
    }
    __syncthreads();

    int co_l = t & 63, slot = t >> 6;
    int co = cot * 64 + co_l;
    float bv = bias[co];
    for (int r5 = 0; r5 < 5; ++r5) {
        int py = slot * 5 + r5;
        float acc[20];
        #pragma unroll
        for (int i = 0; i < 20; i++) acc[i] = bv;
        #pragma unroll
        for (int ky = 0; ky < 9; ++ky) {
            float xr[28];
            const float4* rowp = (const float4*)&xs[(py + ky) * 28];
            #pragma unroll
            for (int q = 0; q < 7; q++) {
                float4 v4 = rowp[q];
                xr[4*q] = v4.x; xr[4*q+1] = v4.y; xr[4*q+2] = v4.z; xr[4*q+3] = v4.w;
            }
            #pragma unroll
            for (int kx = 0; kx < 9; ++kx) {
                float wv = wl[co_l * 81 + ky * 9 + kx];
                #pragma unroll
                for (int px = 0; px < 20; ++px) acc[px] += wv * xr[px + kx];
            }
        }
        #pragma unroll
        for (int px = 0; px < 20; ++px) {
            float v = acc[px];
            unsigned short h = f16bits(v);
            unsigned short l = f16bits(v - f16back(h));
            size_t pix = (size_t)n * 400 + py * 20 + px;
            xpack[pix * 512 + co] = h;
            xpack[pix * 512 + 256 + co] = l;
        }
    }
}

// ---------------- weight repack: w[co][ci][9][9] -> frag-linear single fp16 ----------------
__global__ __launch_bounds__(256) void wpack_kernel(
    const float* __restrict__ w, unsigned short* __restrict__ wp)
{
    int tid = blockIdx.x * 256 + threadIdx.x;
    if (tid >= 648 * 16 * 64) return;
    int lane = tid & 63, g = (tid >> 6) & 15, gs = tid >> 10;
    int cb = gs & 7, kk = gs >> 3;
    int ky = kk / 9, kx = kk - ky * 9;
    int n16 = lane & 15, q = lane >> 4;
    int co = g * 16 + n16;
    unsigned short hv[8];
    #pragma unroll
    for (int j = 0; j < 8; ++j) {
        int ci = cb * 32 + q * 8 + j;
        hv[j] = f16bits(w[((size_t)co * 256 + ci) * 81 + ky * 9 + kx]);
    }
    unsigned short* dst = wp + ((size_t)gs * 16 + g) * 512 + lane * 8;
    *(short8*)dst = *(short8*)hv;
}

// ---------------- pconv GEMM: M48 x N256 x kc-split 4, 2-term fp16 (R14 best) ----------------
__global__ __launch_bounds__(256, 3) void pconv_mfma_kernel(
    const unsigned short* __restrict__ xp, const unsigned short* __restrict__ wp,
    __half* __restrict__ P6)
{
    __shared__ unsigned char lds[49152];        // 36KB used + pad (residency cap 3)
    int t = threadIdx.x;
    int lane = t & 63;
    int w = __builtin_amdgcn_readfirstlane(t >> 6);
    int mtile = blockIdx.x, kc = blockIdx.y;    // 192 mtiles x 48 rows, 4 kc of 162 gs
    int m16 = lane & 15, q = lane >> 4;

    unsigned int asrc[2];
    #pragma unroll
    for (int j = 0; j < 2; ++j) {
        int r = w * 16 + j * 8 + (lane >> 3);   // waves 0..2 stage rows 0..47
        if (r > 47) r = 47;                     // wave 3: arithmetic only, never loads
        int m = mtile * 48 + r;
        int n = m / 36, pos = m - n * 36;
        int oy = pos / 6, ox = pos - oy * 6;
        int pixbase = n * 400 + oy * 40 + ox * 2;
        int pp = (lane & 7) ^ (lane >> 3);       // XOR swizzle
        int partoff = (pp < 4) ? pp * 16 : 512 + (pp - 4) * 16;
        asrc[j] = (unsigned int)(pixbase * 1024 + partoff);
    }
    const char* xb = (const char*)xp;
    const char* wb = (const char*)wp;

    floatx4 acc[3][4];
    #pragma unroll
    for (int a = 0; a < 3; ++a)
        #pragma unroll
        for (int b = 0; b < 4; ++b) acc[a][b] = (floatx4){0.f, 0.f, 0.f, 0.f};

    int slot_hi = (q ^ (m16 & 7)) * 16;
    int slot_lo = slot_hi ^ 64;

    auto stageP = [&](int p, int buf) {
        if (w < 3) {
            #pragma unroll
            for (int e = 0; e < 2; ++e) {
                int s = 2 * p + e; if (s > 161) s = 161;
                int gs = kc * 162 + s;
                int kk = gs >> 3, cb = gs & 7;
                int ky = kk / 9, kx = kk - ky * 9;
                unsigned int delta = (unsigned int)((ky * 20 + kx) * 1024 + cb * 64);
                #pragma unroll
                for (int j = 0; j < 2; ++j)
                    load_lds16(xb + asrc[j] + delta,
                               (void*)(lds + buf * 12288 + e * 6144 + w * 2048 + j * 1024));
            }
        }
    };
    auto loadB = [&](int s, half8* B) {
        if (s > 161) s = 161;
        int gs = kc * 162 + s;
        #pragma unroll
        for (int c = 0; c < 4; ++c)
            B[c] = *(const half8*)(wb + ((size_t)gs * 16 + (w * 4 + c)) * 1024 + lane * 16);
    };
    auto compute = [&](int buf, int e, half8* B) {
        #pragma unroll
        for (int ms = 0; ms < 3; ++ms) {
            const char* base = (const char*)lds + buf * 12288 + e * 6144 + (ms * 16 + m16) * 128;
            half8 Ah = *(const half8*)(base + slot_hi);
            half8 Al = *(const half8*)(base + slot_lo);
            #pragma unroll
            for (int c = 0; c < 4; ++c) {
                acc[ms][c] = __builtin_amdgcn_mfma_f32_16x16x32_f16(Ah, B[c], acc[ms][c], 0, 0, 0);
                acc[ms][c] = __builtin_amdgcn_mfma_f32_16x16x32_f16(Al, B[c], acc[ms][c], 0, 0, 0);
            }
        }
    };

    half8 Ba0[4], Ba1[4], Bb0[4], Bb1[4];

    stageP(0, 0);
    stageP(1, 1);
    loadB(0, Ba0); loadB(1, Ba1);
    asm volatile("s_waitcnt vmcnt(12)" ::: "memory");
    __builtin_amdgcn_s_barrier();

#define PSTEP(PI, BUF, NBUF, C0, C1, N0, N1)                    \
    stageP((PI) + 2, NBUF);                                     \
    loadB(2 * (PI) + 2, N0); loadB(2 * (PI) + 3, N1);           \
    compute(BUF, 0, C0); compute(BUF, 1, C1);                   \
    asm volatile("s_waitcnt vmcnt(12)" ::: "memory");           \
    __builtin_amdgcn_s_barrier();

    for (int p = 0; p < 78; p += 6) {
        PSTEP(p + 0, 0, 2, Ba0, Ba1, Bb0, Bb1)
        PSTEP(p + 1, 1, 0, Bb0, Bb1, Ba0, Ba1)
        PSTEP(p + 2, 2, 1, Ba0, Ba1, Bb0, Bb1)
        PSTEP(p + 3, 0, 2, Bb0, Bb1, Ba0, Ba1)
        PSTEP(p + 4, 1, 0, Ba0, Ba1, Bb0, Bb1)
        PSTEP(p + 5, 2, 1, Bb0, Bb1, Ba0, Ba1)
    }
    PSTEP(78, 0, 2, Ba0, Ba1, Bb0, Bb1)
    PSTEP(79, 1, 0, Bb0, Bb1, Ba0, Ba1)
    PSTEP(80, 2, 1, Ba0, Ba1, Bb0, Bb1)
#undef PSTEP

    __half* outp = P6 + ((size_t)kc * 9216 + (size_t)mtile * 48) * 256;
    #pragma unroll
    for (int ms = 0; ms < 3; ++ms)
        #pragma unroll
        for (int r = 0; r < 4; ++r) {
            int ml = ms * 16 + q * 4 + r;
            #pragma unroll
            for (int c = 0; c < 4; ++c) {
                int co = w * 64 + c * 16 + m16;
                outp[ml * 256 + co] = __float2half(acc[ms][c][r]);
            }
        }
}

// ---------------- reduce 4 fp16 kc-partials + bias + squash over 8-dim capsules ----------------
__global__ __launch_bounds__(256) void squash_u_kernel(
    const __half* __restrict__ P6, const float* __restrict__ pb, float* __restrict__ u)
{
    int cap = blockIdx.x * 256 + threadIdx.x;
    int n = cap / 1152;
    int capl = cap - n * 1152;
    float z[8]; float n2 = 0.f;
    #pragma unroll
    for (int b = 0; b < 8; ++b) {
        int q2 = capl * 8 + b;
        int co = q2 / 36;
        int pos = q2 - co * 36;
        int m = n * 36 + pos;
        float s = 0.f;
        #pragma unroll
        for (int kc = 0; kc < 4; ++kc)
            s += __half2float(P6[((size_t)kc * 9216 + m) * 256 + co]);
        s += pb[co];
        z[b] = s; n2 += s * s;
    }
    float sc = sqrtf(n2) / (1.0f + n2);
    float4* op = (float4*)(u + (size_t)cap * 8);
    op[0] = make_float4(z[0]*sc, z[1]*sc, z[2]*sc, z[3]*sc);
    op[1] = make_float4(z[4]*sc, z[5]*sc, z[6]*sc, z[7]*sc);
}

// ---------------- s partials with fused softmax: block = 32n x ALL j x 12i ----------------
__global__ __launch_bounds__(256, 2) void s_kernel(
    const float* __restrict__ b, const float* __restrict__ u,
    const float* __restrict__ W, float* __restrict__ sbuf)
{
    __shared__ float cs[12][10];
    int t = threadIdx.x;
    int a = t & 15, nl = t >> 4;
    int nt = blockIdx.x;
    int bz = blockIdx.y;              // 96 i-tiles of 12
    int i0 = bz * 12;
    int n0 = nt * 32 + nl * 2;

    if (t < 12) {
        int i = i0 + t;
        float e[10], m = -1e30f;
        #pragma unroll
        for (int j = 0; j < 10; j++) { e[j] = b[i * 10 + j]; m = fmaxf(m, e[j]); }
        float sum = 0.f;
        #pragma unroll
        for (int j = 0; j < 10; j++) { e[j] = expf(e[j] - m); sum += e[j]; }
        float inv = 1.f / sum;
        #pragma unroll
        for (int j = 0; j < 10; j++) cs[t][j] = e[j] * inv;
    }
    __syncthreads();

    float acc[2][10];
    #pragma unroll
    for (int r = 0; r < 2; ++r)
        #pragma unroll
        for (int j = 0; j < 10; ++j) acc[r][j] = 0.f;

    for (int i = i0; i < i0 + 12; ++i) {
        float4 u0[2], u1[2];
        #pragma unroll
        for (int r = 0; r < 2; ++r) {
            const float4* up = (const float4*)&u[(size_t)(n0 + r) * 9216 + (size_t)i * 8];
            u0[r] = up[0]; u1[r] = up[1];
        }
        #pragma unroll
        for (int j = 0; j < 10; ++j) {
            const float4* wpt = (const float4*)&W[(((size_t)i * 10 + j) * 16 + a) * 8];
            float4 w0 = wpt[0], w1 = wpt[1];
            float cij = cs[i - i0][j];
            #pragma unroll
            for (int r = 0; r < 2; ++r) {
                float d = w0.x*u0[r].x + w0.y*u0[r].y + w0.z*u0[r].z + w0.w*u0[r].w
                        + w1.x*u1[r].x + w1.y*u1[r].y + w1.z*u1[r].z + w1.w*u1[r].w;
                acc[r][j] += cij * d;
            }
        }
    }
    #pragma unroll
    for (int r = 0; r < 2; ++r)
        #pragma unroll
        for (int j = 0; j < 10; ++j)
            sbuf[(size_t)bz * 40960 + (((size_t)(n0 + r) * 10 + j) * 16) + a] = acc[r][j];
}

// ---------------- v = squash(sum of 96 s-partials); 160 blocks, shfl norm ----------------
__global__ __launch_bounds__(256) void squash_v_kernel(const float* __restrict__ sbuf,
                                float* __restrict__ v, float* __restrict__ vout)
{
    int t = threadIdx.x;
    int a = t & 15;
    int idx = blockIdx.x * 16 + (t >> 4);
    float s = 0.f;
    #pragma unroll
    for (int z = 0; z < 96; ++z) s += sbuf[(size_t)z * 40960 + idx * 16 + a];
    float n2 = s * s;
    n2 += __shfl_xor(n2, 1);
    n2 += __shfl_xor(n2, 2);
    n2 += __shfl_xor(n2, 4);
    n2 += __shfl_xor(n2, 8);
    float sc = sqrtf(n2) / (1.0f + n2);
    float y = s * sc;
    v[idx * 16 + a] = y;
    if (vout) vout[idx * 16 + a] = y;
}

// ---------------- b[i,j] update, i-tile of 4, n-tile of 64 per block ----------------
__global__ __launch_bounds__(192) void bupd_kernel(
    const float* __restrict__ u, const float* __restrict__ v,
    const float* __restrict__ W, float* __restrict__ b)
{
    int i0 = blockIdx.x * 4;
    int n0 = blockIdx.y * 64;
    int t = threadIdx.x;
    if (t >= 160) return;
    int j = t >> 4, a = t & 15;
    float g4[4][8];
    #pragma unroll
    for (int g = 0; g < 4; ++g)
        #pragma unroll
        for (int k = 0; k < 8; ++k) g4[g][k] = 0.f;

    for (int n = n0; n < n0 + 64; ++n) {
        float vv = v[n * 160 + t];
        const float4* ub = (const float4*)&u[(size_t)n * 9216 + (size_t)i0 * 8];
        #pragma unroll
        for (int g = 0; g < 4; ++g) {
            float4 q0 = ub[g * 2], q1 = ub[g * 2 + 1];
            g4[g][0] += q0.x * vv; g4[g][1] += q0.y * vv; g4[g][2] += q0.z * vv; g4[g][3] += q0.w * vv;
            g4[g][4] += q1.x * vv; g4[g][5] += q1.y * vv; g4[g][6] += q1.z * vv; g4[g][7] += q1.w * vv;
        }
    }
    #pragma unroll
    for (int g = 0; g < 4; ++g) {
        int i = i0 + g;
        const float4* wpt = (const float4*)&W[(((size_t)i * 10 + j) * 16 + a) * 8];
        float4 w0 = wpt[0], w1 = wpt[1];
        float p = w0.x*g4[g][0] + w0.y*g4[g][1] + w0.z*g4[g][2] + w0.w*g4[g][3]
                + w1.x*g4[g][4] + w1.y*g4[g][5] + w1.z*g4[g][6] + w1.w*g4[g][7];
        p += __shfl_xor(p, 1);
        p += __shfl_xor(p, 2);
        p += __shfl_xor(p, 4);
        p += __shfl_xor(p, 8);
        if (a == 0) atomicAdd(&b[i * 10 + j], p);
    }
}

// ---------------- argmax(|v|) + mask -> decoder input (256,160); 16 blocks ----------------
__global__ __launch_bounds__(256) void mask_kernel(const float* __restrict__ v, float* __restrict__ out)
{
    int t = threadIdx.x;
    int a = t & 15, nl = t >> 4;
    int n = blockIdx.x * 16 + nl;
    const float* vp = &v[n * 160];
    int best = 0; float bestn2 = -1.f;
    #pragma unroll
    for (int j = 0; j < 10; ++j) {
        float y = vp[j * 16 + a];
        float n2 = y * y;
        n2 += __shfl_xor(n2, 1);
        n2 += __shfl_xor(n2, 2);
        n2 += __shfl_xor(n2, 4);
        n2 += __shfl_xor(n2, 8);
        if (n2 > bestn2) { bestn2 = n2; best = j; }   // strict > = first max
    }
    #pragma unroll
    for (int j = 0; j < 10; ++j)
        out[n * 160 + j * 16 + a] = (j == best) ? vp[j * 16 + a] : 0.f;
}

// ---------------- MLP partial: templated K, chunked; 16n x 256o per block ----------------
template<int K, int KCH, int O>
__global__ __launch_bounds__(256, 2) void mlp_part_kernel(
    const float* __restrict__ X, const float* __restrict__ Wm,
    float* __restrict__ partial)
{
    __shared__ float XS[KCH * 16];
    int t = threadIdx.x;
    int og = t & 63, ns = t >> 6;
    int n0 = blockIdx.x * 16;
    int o = blockIdx.y * 256 + og * 4;
    int o_c = min(o, O - 4);
    int ks = blockIdx.z;
    int kc0 = ks * KCH;

    for (int idx = t; idx < KCH * 16; idx += 256) {
        int k_l = idx >> 4, n_l = idx & 15;
        XS[k_l * 16 + n_l] = X[(size_t)(n0 + n_l) * K + kc0 + k_l];
    }
    __syncthreads();

    float acc[4][4];
    #pragma unroll
    for (int r = 0; r < 4; ++r)
        #pragma unroll
        for (int q = 0; q < 4; ++q) acc[r][q] = 0.f;

    #pragma unroll 8
    for (int k = 0; k < KCH; ++k) {
        float4 wv = *(const float4*)&Wm[(size_t)(kc0 + k) * O + o_c];
        float4 xs4 = *(const float4*)&XS[k * 16 + ns * 4];
        acc[0][0] += xs4.x * wv.x; acc[0][1] += xs4.x * wv.y; acc[0][2] += xs4.x * wv.z; acc[0][3] += xs4.x * wv.w;
        acc[1][0] += xs4.y * wv.x; acc[1][1] += xs4.y * wv.y; acc[1][2] += xs4.y * wv.z; acc[1][3] += xs4.y * wv.w;
        acc[2][0] += xs4.z * wv.x; acc[2][1] += xs4.z * wv.y; acc[2][2] += xs4.z * wv.z; acc[2][3] += xs4.z * wv.w;
        acc[3][0] += xs4.w * wv.x; acc[3][1] += xs4.w * wv.y; acc[3][2] += xs4.w * wv.z; acc[3][3] += xs4.w * wv.w;
    }

    if (o < O) {
        float* pp = partial + ((size_t)ks * 256 + n0 + ns * 4) * O + o;
        #pragma unroll
        for (int r = 0; r < 4; ++r)
            *(float4*)(pp + (size_t)r * O) = make_float4(acc[r][0], acc[r][1], acc[r][2], acc[r][3]);
    }
}

// ---------------- MLP reduce: out[n][o] = act(sum_ks partial + bias) ----------------
template<int KS, int O, int ACT>
__global__ __launch_bounds__(256) void mlp_reduce_kernel(
    const float* __restrict__ partial, const float* __restrict__ bias,
    float* __restrict__ out)
{
    int n = blockIdx.y;
    int o = (blockIdx.x * 256 + threadIdx.x) * 4;
    if (o >= O) return;
    float4 s = make_float4(0.f, 0.f, 0.f, 0.f);
    #pragma unroll
    for (int ks = 0; ks < KS; ++ks) {
        float4 p = *(const float4*)&partial[((size_t)ks * 256 + n) * O + o];
        s.x += p.x; s.y += p.y; s.z += p.z; s.w += p.w;
    }
    float4 bv = *(const float4*)&bias[o];
    float r[4] = {s.x + bv.x, s.y + bv.y, s.z + bv.z, s.w + bv.w};
    #pragma unroll
    for (int q = 0; q < 4; ++q)
        r[q] = (ACT == 0) ? fmaxf(r[q], 0.f) : (1.f / (1.f + expf(-r[q])));
    *(float4*)&out[(size_t)n * O + o] = make_float4(r[0], r[1], r[2], r[3]);
}

extern "C" void kernel_launch(void* const* d_in, const int* in_sizes, int n_in,
                              void* d_out, int out_size, void* d_ws, size_t ws_size,
                              hipStream_t stream)
{
    const float* x       = (const float*)d_in[0];
    const float* conv1_w = (const float*)d_in[1];
    const float* conv1_b = (const float*)d_in[2];
    const float* pconv_w = (const float*)d_in[3];
    const float* pconv_b = (const float*)d_in[4];
    const float* W_caps  = (const float*)d_in[5];
    const float* dec_w1  = (const float*)d_in[6];
    const float* dec_b1  = (const float*)d_in[7];
    const float* dec_w2  = (const float*)d_in[8];
    const float* dec_b2  = (const float*)d_in[9];
    const float* dec_w3  = (const float*)d_in[10];
    const float* dec_b3  = (const float*)d_in[11];
    float* out = (float*)d_out;

    float* ws = (float*)d_ws;
    size_t off = 0;
    auto alloc = [&](size_t nf) { float* p = ws + off; off += (nf + 63) & ~(size_t)63; return p; };
    unsigned short* xpack = (unsigned short*)alloc(26214400);  // 256*400*512 ushort
    unsigned short* wpack = (unsigned short*)alloc(2654208);   // 648*16*512 ushort
    __half* P6  = (__half*)alloc(4718592);   // 4*9216*256 fp16 partials
    float* u_in = alloc(2359296);
    float* bbuf = alloc(11520);
    float* sbuf = alloc(96 * 40960);
    float* vbuf = alloc(40960);
    float* rin  = alloc(40960);
    float* mpart = alloc(8 * 256 * 1024);
    float* h1   = alloc(131072);
    float* h2   = alloc(262144);

    hipMemsetAsync(bbuf, 0, 11520 * sizeof(float), stream);

    wpack_kernel<<<(648 * 16 * 64 + 255) / 256, 256, 0, stream>>>(pconv_w, wpack);
    conv1_kernel<<<dim3(256, 4), 256, 0, stream>>>(x, conv1_w, conv1_b, xpack);
    pconv_mfma_kernel<<<dim3(192, 4), 256, 0, stream>>>(xpack, wpack, P6);
    squash_u_kernel<<<1152, 256, 0, stream>>>(P6, pconv_b, u_in);

    for (int r = 0; r < 4; ++r) {
        s_kernel<<<dim3(8, 96), 256, 0, stream>>>(bbuf, u_in, W_caps, sbuf);
        squash_v_kernel<<<160, 256, 0, stream>>>(sbuf, vbuf, (r == 3) ? out : nullptr);
        if (r < 3) bupd_kernel<<<dim3(288, 4), 192, 0, stream>>>(u_in, vbuf, W_caps, bbuf);
    }

    mask_kernel<<<16, 256, 0, stream>>>(vbuf, rin);

    mlp_part_kernel<160, 80, 512><<<dim3(16, 2, 2), 256, 0, stream>>>(rin, dec_w1, mpart);
    mlp_reduce_kernel<2, 512, 0><<<dim3(1, 256), 256, 0, stream>>>(mpart, dec_b1, h1);
    mlp_part_kernel<512, 128, 1024><<<dim3(16, 4, 4), 256, 0, stream>>>(h1, dec_w2, mpart);
    mlp_reduce_kernel<4, 1024, 0><<<dim3(1, 256), 256, 0, stream>>>(mpart, dec_b2, h2);
    mlp_part_kernel<1024, 128, 784><<<dim3(16, 4, 8), 256, 0, stream>>>(h2, dec_w3, mpart);
    mlp_reduce_kernel<8, 784, 1><<<dim3(1, 256), 256, 0, stream>>>(mpart, dec_b3, out + 40960);
}

// Round 10
// 692.345 us; speedup vs baseline: 1.3895x; 1.0603x over previous
//
#include <hip/hip_runtime.h>
#include <hip/hip_fp16.h>
#include <math.h>

// CapsNet forward. Round 20: exact R14 kernel set (best measured: pconv 165.9,
// total 710; R19 routing re-tile reverted - it traded occupancy for 2x sbuf
// traffic and lost). One new lever: T1 XCD-aware bijective swizzle of pconv's
// (mtile,kc) mapping. Default round-robin puts ADJACENT mtiles (sharing ~78%
// of overlapping stride-2 input patches) on DIFFERENT XCD L2s -> each XCD
// streams the whole 105MB xpack (FETCH 263MB @ ~2TB/s ~ kernel duration).
// swz = (f%8)*96 + f/8 gives each XCD 96 consecutive mtiles of one kc slice
// (~6MB working set ~ L2 size) -> overlapping patches hit L2.

typedef __attribute__((ext_vector_type(8))) _Float16 half8;
typedef __attribute__((ext_vector_type(8))) short short8;
typedef __attribute__((ext_vector_type(4))) float floatx4;

__device__ __forceinline__ unsigned short f16bits(float v) {
    _Float16 h = (_Float16)v;
    unsigned short b;
    __builtin_memcpy(&b, &h, 2);
    return b;
}
__device__ __forceinline__ float f16back(unsigned short b) {
    _Float16 h;
    __builtin_memcpy(&h, &b, 2);
    return (float)h;
}
__device__ __forceinline__ void load_lds16(const void* g, void* l) {
    __builtin_amdgcn_global_load_lds(
        (const __attribute__((address_space(1))) unsigned int*)g,
        (__attribute__((address_space(3))) unsigned int*)l, 16, 0, 0);
}

// ---------------- conv1: x(256,1,28,28) * w(256,81) -> xpack NHWC fp16 hi/lo ----------------
__global__ __launch_bounds__(256, 2) void conv1_kernel(
    const float* __restrict__ x, const float* __restrict__ w,
    const float* __restrict__ bias, unsigned short* __restrict__ xpack)
{
    __shared__ float xs[784];
    __shared__ float wl[64 * 81];
    int t = threadIdx.x;
    int n = blockIdx.x;
    int cot = blockIdx.y;

    for (int j = t; j < 784; j += 256) xs[j] = x[n * 784 + j];
    {
        int co_s = t >> 2, k0 = (t & 3) * 21;
        const float* wsrc = w + (size_t)(cot * 64 + co_s) * 81;
        #pragma unroll
        for (int k = 0; k < 21; ++k)
            if (k0 + k < 81) wl[co_s * 81 + k0 + k] = wsrc[k0 + k];
    }
    __syncthreads();

    int co_l = t & 63, slot = t >> 6;
    int co = cot * 64 + co_l;
    float bv = bias[co];
    for (int r5 = 0; r5 < 5; ++r5) {
        int py = slot * 5 + r5;
        float acc[20];
        #pragma unroll
        for (int i = 0; i < 20; i++) acc[i] = bv;
        #pragma unroll
        for (int ky = 0; ky < 9; ++ky) {
            float xr[28];
            const float4* rowp = (const float4*)&xs[(py + ky) * 28];
            #pragma unroll
            for (int q = 0; q < 7; q++) {
                float4 v4 = rowp[q];
                xr[4*q] = v4.x; xr[4*q+1] = v4.y; xr[4*q+2] = v4.z; xr[4*q+3] = v4.w;
            }
            #pragma unroll
            for (int kx = 0; kx < 9; ++kx) {
                float wv = wl[co_l * 81 + ky * 9 + kx];
                #pragma unroll
                for (int px = 0; px < 20; ++px) acc[px] += wv * xr[px + kx];
            }
        }
        #pragma unroll
        for (int px = 0; px < 20; ++px) {
            float v = acc[px];
            unsigned short h = f16bits(v);
            unsigned short l = f16bits(v - f16back(h));
            size_t pix = (size_t)n * 400 + py * 20 + px;
            xpack[pix * 512 + co] = h;
            xpack[pix * 512 + 256 + co] = l;
        }
    }
}

// ---------------- weight repack: w[co][ci][9][9] -> frag-linear single fp16 ----------------
__global__ __launch_bounds__(256) void wpack_kernel(
    const float* __restrict__ w, unsigned short* __restrict__ wp)
{
    int tid = blockIdx.x * 256 + threadIdx.x;
    if (tid >= 648 * 16 * 64) return;
    int lane = tid & 63, g = (tid >> 6) & 15, gs = tid >> 10;
    int cb = gs & 7, kk = gs >> 3;
    int ky = kk / 9, kx = kk - ky * 9;
    int n16 = lane & 15, q = lane >> 4;
    int co = g * 16 + n16;
    unsigned short hv[8];
    #pragma unroll
    for (int j = 0; j < 8; ++j) {
        int ci = cb * 32 + q * 8 + j;
        hv[j] = f16bits(w[((size_t)co * 256 + ci) * 81 + ky * 9 + kx]);
    }
    unsigned short* dst = wp + ((size_t)gs * 16 + g) * 512 + lane * 8;
    *(short8*)dst = *(short8*)hv;
}

// ---------------- pconv GEMM: M48 x N256 x kc-split 4, 2-term fp16 ----------------
// 768 blocks, 3/CU (48KB LDS pad). XCD-swizzled (mtile,kc). 3-buf rotation,
// stage 2 pairs ahead, B 1 pair ahead, vmcnt(12) + raw s_barrier.
__global__ __launch_bounds__(256, 3) void pconv_mfma_kernel(
    const unsigned short* __restrict__ xp, const unsigned short* __restrict__ wp,
    __half* __restrict__ P6)
{
    __shared__ unsigned char lds[49152];        // 36KB used + pad (residency cap 3)
    int t = threadIdx.x;
    int lane = t & 63;
    int w = __builtin_amdgcn_readfirstlane(t >> 6);
    // XCD-aware bijective swizzle: f = kc*192 + mtile dispatch id; XCD = f%8.
    // swz groups 96 consecutive mtiles (one kc slice) per XCD -> patch overlap
    // between adjacent mtiles becomes an L2 hit instead of an HBM refetch.
    int f = blockIdx.y * 192 + blockIdx.x;
    int swz = (f & 7) * 96 + (f >> 3);
    int mtile = swz % 192, kc = swz / 192;      // 192 mtiles x 48 rows, 4 kc of 162 gs
    int m16 = lane & 15, q = lane >> 4;

    unsigned int asrc[2];
    #pragma unroll
    for (int j = 0; j < 2; ++j) {
        int r = w * 16 + j * 8 + (lane >> 3);   // waves 0..2 stage rows 0..47
        if (r > 47) r = 47;                     // wave 3: arithmetic only, never loads
        int m = mtile * 48 + r;
        int n = m / 36, pos = m - n * 36;
        int oy = pos / 6, ox = pos - oy * 6;
        int pixbase = n * 400 + oy * 40 + ox * 2;
        int pp = (lane & 7) ^ (lane >> 3);       // XOR swizzle
        int partoff = (pp < 4) ? pp * 16 : 512 + (pp - 4) * 16;
        asrc[j] = (unsigned int)(pixbase * 1024 + partoff);
    }
    const char* xb = (const char*)xp;
    const char* wb = (const char*)wp;

    floatx4 acc[3][4];
    #pragma unroll
    for (int a = 0; a < 3; ++a)
        #pragma unroll
        for (int b = 0; b < 4; ++b) acc[a][b] = (floatx4){0.f, 0.f, 0.f, 0.f};

    int slot_hi = (q ^ (m16 & 7)) * 16;
    int slot_lo = slot_hi ^ 64;

    auto stageP = [&](int p, int buf) {
        if (w < 3) {
            #pragma unroll
            for (int e = 0; e < 2; ++e) {
                int s = 2 * p + e; if (s > 161) s = 161;
                int gs = kc * 162 + s;
                int kk = gs >> 3, cb = gs & 7;
                int ky = kk / 9, kx = kk - ky * 9;
                unsigned int delta = (unsigned int)((ky * 20 + kx) * 1024 + cb * 64);
                #pragma unroll
                for (int j = 0; j < 2; ++j)
                    load_lds16(xb + asrc[j] + delta,
                               (void*)(lds + buf * 12288 + e * 6144 + w * 2048 + j * 1024));
            }
        }
    };
    auto loadB = [&](int s, half8* B) {
        if (s > 161) s = 161;
        int gs = kc * 162 + s;
        #pragma unroll
        for (int c = 0; c < 4; ++c)
            B[c] = *(const half8*)(wb + ((size_t)gs * 16 + (w * 4 + c)) * 1024 + lane * 16);
    };
    auto compute = [&](int buf, int e, half8* B) {
        #pragma unroll
        for (int ms = 0; ms < 3; ++ms) {
            const char* base = (const char*)lds + buf * 12288 + e * 6144 + (ms * 16 + m16) * 128;
            half8 Ah = *(const half8*)(base + slot_hi);
            half8 Al = *(const half8*)(base + slot_lo);
            #pragma unroll
            for (int c = 0; c < 4; ++c) {
                acc[ms][c] = __builtin_amdgcn_mfma_f32_16x16x32_f16(Ah, B[c], acc[ms][c], 0, 0, 0);
                acc[ms][c] = __builtin_amdgcn_mfma_f32_16x16x32_f16(Al, B[c], acc[ms][c], 0, 0, 0);
            }
        }
    };

    half8 Ba0[4], Ba1[4], Bb0[4], Bb1[4];

    stageP(0, 0);
    stageP(1, 1);
    loadB(0, Ba0); loadB(1, Ba1);
    asm volatile("s_waitcnt vmcnt(12)" ::: "memory");
    __builtin_amdgcn_s_barrier();

#define PSTEP(PI, BUF, NBUF, C0, C1, N0, N1)                    \
    stageP((PI) + 2, NBUF);                                     \
    loadB(2 * (PI) + 2, N0); loadB(2 * (PI) + 3, N1);           \
    compute(BUF, 0, C0); compute(BUF, 1, C1);                   \
    asm volatile("s_waitcnt vmcnt(12)" ::: "memory");           \
    __builtin_amdgcn_s_barrier();

    for (int p = 0; p < 78; p += 6) {
        PSTEP(p + 0, 0, 2, Ba0, Ba1, Bb0, Bb1)
        PSTEP(p + 1, 1, 0, Bb0, Bb1, Ba0, Ba1)
        PSTEP(p + 2, 2, 1, Ba0, Ba1, Bb0, Bb1)
        PSTEP(p + 3, 0, 2, Bb0, Bb1, Ba0, Ba1)
        PSTEP(p + 4, 1, 0, Ba0, Ba1, Bb0, Bb1)
        PSTEP(p + 5, 2, 1, Bb0, Bb1, Ba0, Ba1)
    }
    PSTEP(78, 0, 2, Ba0, Ba1, Bb0, Bb1)
    PSTEP(79, 1, 0, Bb0, Bb1, Ba0, Ba1)
    PSTEP(80, 2, 1, Ba0, Ba1, Bb0, Bb1)
#undef PSTEP

    __half* outp = P6 + ((size_t)kc * 9216 + (size_t)mtile * 48) * 256;
    #pragma unroll
    for (int ms = 0; ms < 3; ++ms)
        #pragma unroll
        for (int r = 0; r < 4; ++r) {
            int ml = ms * 16 + q * 4 + r;
            #pragma unroll
            for (int c = 0; c < 4; ++c) {
                int co = w * 64 + c * 16 + m16;
                outp[ml * 256 + co] = __float2half(acc[ms][c][r]);
            }
        }
}

// ---------------- reduce 4 fp16 kc-partials + bias + squash over 8-dim capsules ----------------
__global__ __launch_bounds__(256) void squash_u_kernel(
    const __half* __restrict__ P6, const float* __restrict__ pb, float* __restrict__ u)
{
    int cap = blockIdx.x * 256 + threadIdx.x;
    int n = cap / 1152;
    int capl = cap - n * 1152;
    float z[8]; float n2 = 0.f;
    #pragma unroll
    for (int b = 0; b < 8; ++b) {
        int q2 = capl * 8 + b;
        int co = q2 / 36;
        int pos = q2 - co * 36;
        int m = n * 36 + pos;
        float s = 0.f;
        #pragma unroll
        for (int kc = 0; kc < 4; ++kc)
            s += __half2float(P6[((size_t)kc * 9216 + m) * 256 + co]);
        s += pb[co];
        z[b] = s; n2 += s * s;
    }
    float sc = sqrtf(n2) / (1.0f + n2);
    float4* op = (float4*)(u + (size_t)cap * 8);
    op[0] = make_float4(z[0]*sc, z[1]*sc, z[2]*sc, z[3]*sc);
    op[1] = make_float4(z[4]*sc, z[5]*sc, z[6]*sc, z[7]*sc);
}

// ---------------- s partials with fused softmax: block = 32n x ALL j x 24i ----------------
__global__ __launch_bounds__(256, 2) void s_kernel(
    const float* __restrict__ b, const float* __restrict__ u,
    const float* __restrict__ W, float* __restrict__ sbuf)
{
    __shared__ float cs[24][10];
    int t = threadIdx.x;
    int a = t & 15, nl = t >> 4;
    int nt = blockIdx.x;
    int bz = blockIdx.y;
    int i0 = bz * 24;
    int n0 = nt * 32 + nl * 2;

    if (t < 24) {
        int i = i0 + t;
        float e[10], m = -1e30f;
        #pragma unroll
        for (int j = 0; j < 10; j++) { e[j] = b[i * 10 + j]; m = fmaxf(m, e[j]); }
        float sum = 0.f;
        #pragma unroll
        for (int j = 0; j < 10; j++) { e[j] = expf(e[j] - m); sum += e[j]; }
        float inv = 1.f / sum;
        #pragma unroll
        for (int j = 0; j < 10; j++) cs[t][j] = e[j] * inv;
    }
    __syncthreads();

    float acc[2][10];
    #pragma unroll
    for (int r = 0; r < 2; ++r)
        #pragma unroll
        for (int j = 0; j < 10; ++j) acc[r][j] = 0.f;

    for (int i = i0; i < i0 + 24; ++i) {
        float4 u0[2], u1[2];
        #pragma unroll
        for (int r = 0; r < 2; ++r) {
            const float4* up = (const float4*)&u[(size_t)(n0 + r) * 9216 + (size_t)i * 8];
            u0[r] = up[0]; u1[r] = up[1];
        }
        #pragma unroll
        for (int j = 0; j < 10; ++j) {
            const float4* wpt = (const float4*)&W[(((size_t)i * 10 + j) * 16 + a) * 8];
            float4 w0 = wpt[0], w1 = wpt[1];
            float cij = cs[i - i0][j];
            #pragma unroll
            for (int r = 0; r < 2; ++r) {
                float d = w0.x*u0[r].x + w0.y*u0[r].y + w0.z*u0[r].z + w0.w*u0[r].w
                        + w1.x*u1[r].x + w1.y*u1[r].y + w1.z*u1[r].z + w1.w*u1[r].w;
                acc[r][j] += cij * d;
            }
        }
    }
    #pragma unroll
    for (int r = 0; r < 2; ++r)
        #pragma unroll
        for (int j = 0; j < 10; ++j)
            sbuf[(size_t)bz * 40960 + (((size_t)(n0 + r) * 10 + j) * 16) + a] = acc[r][j];
}

// ---------------- v = squash(sum of 48 s-partials); 160 blocks, shfl norm ----------------
__global__ __launch_bounds__(256) void squash_v_kernel(const float* __restrict__ sbuf,
                                float* __restrict__ v, float* __restrict__ vout)
{
    int t = threadIdx.x;
    int a = t & 15;
    int idx = blockIdx.x * 16 + (t >> 4);
    float s = 0.f;
    #pragma unroll
    for (int z = 0; z < 48; ++z) s += sbuf[(size_t)z * 40960 + idx * 16 + a];
    float n2 = s * s;
    n2 += __shfl_xor(n2, 1);
    n2 += __shfl_xor(n2, 2);
    n2 += __shfl_xor(n2, 4);
    n2 += __shfl_xor(n2, 8);
    float sc = sqrtf(n2) / (1.0f + n2);
    float y = s * sc;
    v[idx * 16 + a] = y;
    if (vout) vout[idx * 16 + a] = y;
}

// ---------------- b[i,j] update, i-tile of 4 per block ----------------
__global__ __launch_bounds__(192) void bupd_kernel(
    const float* __restrict__ u, const float* __restrict__ v,
    const float* __restrict__ W, float* __restrict__ b)
{
    int i0 = blockIdx.x * 4;
    int n0 = blockIdx.y * 128;
    int t = threadIdx.x;
    if (t >= 160) return;
    int j = t >> 4, a = t & 15;
    float g4[4][8];
    #pragma unroll
    for (int g = 0; g < 4; ++g)
        #pragma unroll
        for (int k = 0; k < 8; ++k) g4[g][k] = 0.f;

    for (int n = n0; n < n0 + 128; ++n) {
        float vv = v[n * 160 + t];
        const float4* ub = (const float4*)&u[(size_t)n * 9216 + (size_t)i0 * 8];
        #pragma unroll
        for (int g = 0; g < 4; ++g) {
            float4 q0 = ub[g * 2], q1 = ub[g * 2 + 1];
            g4[g][0] += q0.x * vv; g4[g][1] += q0.y * vv; g4[g][2] += q0.z * vv; g4[g][3] += q0.w * vv;
            g4[g][4] += q1.x * vv; g4[g][5] += q1.y * vv; g4[g][6] += q1.z * vv; g4[g][7] += q1.w * vv;
        }
    }
    #pragma unroll
    for (int g = 0; g < 4; ++g) {
        int i = i0 + g;
        const float4* wpt = (const float4*)&W[(((size_t)i * 10 + j) * 16 + a) * 8];
        float4 w0 = wpt[0], w1 = wpt[1];
        float p = w0.x*g4[g][0] + w0.y*g4[g][1] + w0.z*g4[g][2] + w0.w*g4[g][3]
                + w1.x*g4[g][4] + w1.y*g4[g][5] + w1.z*g4[g][6] + w1.w*g4[g][7];
        p += __shfl_xor(p, 1);
        p += __shfl_xor(p, 2);
        p += __shfl_xor(p, 4);
        p += __shfl_xor(p, 8);
        if (a == 0) atomicAdd(&b[i * 10 + j], p);
    }
}

// ---------------- argmax(|v|) + mask -> decoder input (256,160); 16 blocks ----------------
__global__ __launch_bounds__(256) void mask_kernel(const float* __restrict__ v, float* __restrict__ out)
{
    int t = threadIdx.x;
    int a = t & 15, nl = t >> 4;
    int n = blockIdx.x * 16 + nl;
    const float* vp = &v[n * 160];
    int best = 0; float bestn2 = -1.f;
    #pragma unroll
    for (int j = 0; j < 10; ++j) {
        float y = vp[j * 16 + a];
        float n2 = y * y;
        n2 += __shfl_xor(n2, 1);
        n2 += __shfl_xor(n2, 2);
        n2 += __shfl_xor(n2, 4);
        n2 += __shfl_xor(n2, 8);
        if (n2 > bestn2) { bestn2 = n2; best = j; }   // strict > = first max
    }
    #pragma unroll
    for (int j = 0; j < 10; ++j)
        out[n * 160 + j * 16 + a] = (j == best) ? vp[j * 16 + a] : 0.f;
}

// ---------------- MLP partial: templated K, chunked; 16n x 256o per block ----------------
template<int K, int KCH, int O>
__global__ __launch_bounds__(256, 2) void mlp_part_kernel(
    const float* __restrict__ X, const float* __restrict__ Wm,
    float* __restrict__ partial)
{
    __shared__ float XS[KCH * 16];
    int t = threadIdx.x;
    int og = t & 63, ns = t >> 6;
    int n0 = blockIdx.x * 16;
    int o = blockIdx.y * 256 + og * 4;
    int o_c = min(o, O - 4);
    int ks = blockIdx.z;
    int kc0 = ks * KCH;

    for (int idx = t; idx < KCH * 16; idx += 256) {
        int k_l = idx >> 4, n_l = idx & 15;
        XS[k_l * 16 + n_l] = X[(size_t)(n0 + n_l) * K + kc0 + k_l];
    }
    __syncthreads();

    float acc[4][4];
    #pragma unroll
    for (int r = 0; r < 4; ++r)
        #pragma unroll
        for (int q = 0; q < 4; ++q) acc[r][q] = 0.f;

    #pragma unroll 8
    for (int k = 0; k < KCH; ++k) {
        float4 wv = *(const float4*)&Wm[(size_t)(kc0 + k) * O + o_c];
        float4 xs4 = *(const float4*)&XS[k * 16 + ns * 4];
        acc[0][0] += xs4.x * wv.x; acc[0][1] += xs4.x * wv.y; acc[0][2] += xs4.x * wv.z; acc[0][3] += xs4.x * wv.w;
        acc[1][0] += xs4.y * wv.x; acc[1][1] += xs4.y * wv.y; acc[1][2] += xs4.y * wv.z; acc[1][3] += xs4.y * wv.w;
        acc[2][0] += xs4.z * wv.x; acc[2][1] += xs4.z * wv.y; acc[2][2] += xs4.z * wv.z; acc[2][3] += xs4.z * wv.w;
        acc[3][0] += xs4.w * wv.x; acc[3][1] += xs4.w * wv.y; acc[3][2] += xs4.w * wv.z; acc[3][3] += xs4.w * wv.w;
    }

    if (o < O) {
        float* pp = partial + ((size_t)ks * 256 + n0 + ns * 4) * O + o;
        #pragma unroll
        for (int r = 0; r < 4; ++r)
            *(float4*)(pp + (size_t)r * O) = make_float4(acc[r][0], acc[r][1], acc[r][2], acc[r][3]);
    }
}

// ---------------- MLP reduce: out[n][o] = act(sum_ks partial + bias) ----------------
template<int KS, int O, int ACT>
__global__ __launch_bounds__(256) void mlp_reduce_kernel(
    const float* __restrict__ partial, const float* __restrict__ bias,
    float* __restrict__ out)
{
    int n = blockIdx.y;
    int o = (blockIdx.x * 256 + threadIdx.x) * 4;
    if (o >= O) return;
    float4 s = make_float4(0.f, 0.f, 0.f, 0.f);
    #pragma unroll
    for (int ks = 0; ks < KS; ++ks) {
        float4 p = *(const float4*)&partial[((size_t)ks * 256 + n) * O + o];
        s.x += p.x; s.y += p.y; s.z += p.z; s.w += p.w;
    }
    float4 bv = *(const float4*)&bias[o];
    float r[4] = {s.x + bv.x, s.y + bv.y, s.z + bv.z, s.w + bv.w};
    #pragma unroll
    for (int q = 0; q < 4; ++q)
        r[q] = (ACT == 0) ? fmaxf(r[q], 0.f) : (1.f / (1.f + expf(-r[q])));
    *(float4*)&out[(size_t)n * O + o] = make_float4(r[0], r[1], r[2], r[3]);
}

extern "C" void kernel_launch(void* const* d_in, const int* in_sizes, int n_in,
                              void* d_out, int out_size, void* d_ws, size_t ws_size,
                              hipStream_t stream)
{
    const float* x       = (const float*)d_in[0];
    const float* conv1_w = (const float*)d_in[1];
    const float* conv1_b = (const float*)d_in[2];
    const float* pconv_w = (const float*)d_in[3];
    const float* pconv_b = (const float*)d_in[4];
    const float* W_caps  = (const float*)d_in[5];
    const float* dec_w1  = (const float*)d_in[6];
    const float* dec_b1  = (const float*)d_in[7];
    const float* dec_w2  = (const float*)d_in[8];
    const float* dec_b2  = (const float*)d_in[9];
    const float* dec_w3  = (const float*)d_in[10];
    const float* dec_b3  = (const float*)d_in[11];
    float* out = (float*)d_out;

    float* ws = (float*)d_ws;
    size_t off = 0;
    auto alloc = [&](size_t nf) { float* p = ws + off; off += (nf + 63) & ~(size_t)63; return p; };
    unsigned short* xpack = (unsigned short*)alloc(26214400);  // 256*400*512 ushort
    unsigned short* wpack = (unsigned short*)alloc(2654208);   // 648*16*512 ushort
    __half* P6  = (__half*)alloc(4718592);   // 4*9216*256 fp16 partials
    float* u_in = alloc(2359296);
    float* bbuf = alloc(11520);
    float* sbuf = alloc(48 * 40960);
    float* vbuf = alloc(40960);
    float* rin  = alloc(40960);
    float* mpart = alloc(8 * 256 * 1024);
    float* h1   = alloc(131072);
    float* h2   = alloc(262144);

    hipMemsetAsync(bbuf, 0, 11520 * sizeof(float), stream);

    wpack_kernel<<<(648 * 16 * 64 + 255) / 256, 256, 0, stream>>>(pconv_w, wpack);
    conv1_kernel<<<dim3(256, 4), 256, 0, stream>>>(x, conv1_w, conv1_b, xpack);
    pconv_mfma_kernel<<<dim3(192, 4), 256, 0, stream>>>(xpack, wpack, P6);
    squash_u_kernel<<<1152, 256, 0, stream>>>(P6, pconv_b, u_in);

    for (int r = 0; r < 4; ++r) {
        s_kernel<<<dim3(8, 48), 256, 0, stream>>>(bbuf, u_in, W_caps, sbuf);
        squash_v_kernel<<<160, 256, 0, stream>>>(sbuf, vbuf, (r == 3) ? out : nullptr);
        if (r < 3) bupd_kernel<<<dim3(288, 2), 192, 0, stream>>>(u_in, vbuf, W_caps, bbuf);
    }

    mask_kernel<<<16, 256, 0, stream>>>(vbuf, rin);

    mlp_part_kernel<160, 80, 512><<<dim3(16, 2, 2), 256, 0, stream>>>(rin, dec_w1, mpart);
    mlp_reduce_kernel<2, 512, 0><<<dim3(1, 256), 256, 0, stream>>>(mpart, dec_b1, h1);
    mlp_part_kernel<512, 128, 1024><<<dim3(16, 4, 4), 256, 0, stream>>>(h1, dec_w2, mpart);
    mlp_reduce_kernel<4, 1024, 0><<<dim3(1, 256), 256, 0, stream>>>(mpart, dec_b2, h2);
    mlp_part_kernel<1024, 128, 784><<<dim3(16, 4, 8), 256, 0, stream>>>(h2, dec_w3, mpart);
    mlp_reduce_kernel<8, 784, 1><<<dim3(1, 256), 256, 0, stream>>>(mpart, dec_b3, out + 40960);
}